// Round 1
// baseline (6885.275 us; speedup 1.0000x reference)
//
#include <hip/hip_runtime.h>

#define A_DIM 64
#define B_DIM 128
#define E 128
#define NG 50
#define NROW (A_DIM*A_DIM*B_DIM)   // 524288
#define TR 64                      // rows per block
#define XSTR 132                   // padded x-tile row stride (breaks 4-way bank conflict)
#define SSTR 52                    // smeared-gaussian tile row stride (50 padded to 52)

__device__ __forceinline__ float silu_f(float x) {
  // x * sigmoid(x); v_exp + v_rcp are ~1 ulp — plenty for the 8e-5 budget
  return x * __builtin_amdgcn_rcpf(1.0f + __expf(-x));
}

// acc[4][8] += x[r0..r0+3][0..KC) @ wt[0..KC)[c0..c0+7]
template<int KC>
__device__ __forceinline__ void gemm_acc(const float* xbase, int xstride,
                                         const float* wt,
                                         float acc[4][8], int r0, int c0) {
  #pragma unroll
  for (int kl = 0; kl < KC; kl += 4) {
    float4 xv[4];
    #pragma unroll
    for (int rr = 0; rr < 4; ++rr)
      xv[rr] = *(const float4*)(xbase + (r0 + rr) * xstride + kl);
    float4 w0[4], w1[4];
    #pragma unroll
    for (int kk = 0; kk < 4; ++kk) {
      w0[kk] = *(const float4*)(wt + (kl + kk) * E + c0);
      w1[kk] = *(const float4*)(wt + (kl + kk) * E + c0 + 4);
    }
    #pragma unroll
    for (int rr = 0; rr < 4; ++rr) {
      float xr[4] = {xv[rr].x, xv[rr].y, xv[rr].z, xv[rr].w};
      #pragma unroll
      for (int kk = 0; kk < 4; ++kk) {
        acc[rr][0] += xr[kk] * w0[kk].x;
        acc[rr][1] += xr[kk] * w0[kk].y;
        acc[rr][2] += xr[kk] * w0[kk].z;
        acc[rr][3] += xr[kk] * w0[kk].w;
        acc[rr][4] += xr[kk] * w1[kk].x;
        acc[rr][5] += xr[kk] * w1[kk].y;
        acc[rr][6] += xr[kk] * w1[kk].z;
        acc[rr][7] += xr[kk] * w1[kk].w;
      }
    }
  }
}

__device__ __forceinline__ void stage_w32(float* wt, const float* Wg, int t) {
  const float4* g4 = (const float4*)Wg;
  float4* s4 = (float4*)wt;
  #pragma unroll
  for (int i = 0; i < 4; ++i) s4[t + 256 * i] = g4[t + 256 * i];
}

__global__ __launch_bounds__(256, 2) void fused_main(
    const float* __restrict__ T, const float* __restrict__ mask,
    const float* __restrict__ dist,
    const float* __restrict__ eWin, const float* __restrict__ ebin,
    const float* __restrict__ eWh,  const float* __restrict__ ebh,
    const float* __restrict__ eWout,const float* __restrict__ ebout,
    const float* __restrict__ erbf, const float* __restrict__ ehead,
    const float* __restrict__ fWin, const float* __restrict__ fbin,
    const float* __restrict__ fWh,  const float* __restrict__ fbh,
    const float* __restrict__ fWout,const float* __restrict__ fbout,
    const float* __restrict__ frbf, const float* __restrict__ fhead,
    float* __restrict__ em, float* __restrict__ fm)
{
  __shared__ float xs[TR * XSTR];     // 33792 B
  __shared__ float wt[32 * E];        // 16384 B
  __shared__ float smb[TR * SSTR];    // 13312 B
  __shared__ float biasb[E];          // 512 B
  __shared__ float headb[E];          // 512 B   -> 64512 B total

  const int t = threadIdx.x;
  const int rg = t >> 4, cg = t & 15;
  const int r0 = rg * 4, c0 = cg * 8;
  const long r0g = (long)blockIdx.x * TR;

  const float step = 12.0f / 49.0f;
  const float coeff = -0.5f / (step * step);

  for (int br = 0; br < 2; ++br) {
    const float* Win  = br ? fWin  : eWin;
    const float* bin  = br ? fbin  : ebin;
    const float* Wh   = br ? fWh   : eWh;
    const float* bh   = br ? fbh   : ebh;
    const float* Wout = br ? fWout : eWout;
    const float* bout = br ? fbout : ebout;
    const float* rbf  = br ? frbf  : erbf;
    const float* head = br ? fhead : ehead;
    float* outw = br ? fm : em;

    __syncthreads();                  // xs free for reuse
    // ---- load T tile (64 rows x 128) into xs ----
    {
      const float4* T4 = (const float4*)(T + r0g * E);
      #pragma unroll
      for (int i = 0; i < 8; ++i) {
        int f = t + 256 * i;          // 0..2047 float4s
        int r = f >> 5, c4 = f & 31;
        *(float4*)&xs[r * XSTR + c4 * 4] = T4[f];
      }
    }

    float feat[4][8];

    // ---- 4 dense layers ----
    #pragma unroll 1
    for (int lay = 0; lay < 4; ++lay) {
      const float* Wg = (lay == 0) ? Win : (lay == 1) ? Wh : (lay == 2) ? (Wh + E * E) : Wout;
      const float* bg = (lay == 0) ? bin : (lay == 1) ? bh : (lay == 2) ? (bh + E)     : bout;

      float acc[4][8];
      #pragma unroll 1
      for (int kc = 0; kc < 4; ++kc) {
        if (kc == 0 && t < E) biasb[t] = bg[t];
        stage_w32(wt, Wg + kc * 32 * E, t);
        __syncthreads();              // stage done; also orders xs writes (prev layer) before reads
        if (kc == 0) {
          #pragma unroll
          for (int rr = 0; rr < 4; ++rr)
            #pragma unroll
            for (int cc = 0; cc < 8; ++cc) acc[rr][cc] = biasb[c0 + cc];
        }
        gemm_acc<32>(xs + kc * 32, XSTR, wt, acc, r0, c0);
        __syncthreads();              // all reads of wt (and xs) done before next stage
      }

      if (lay == 3) {
        #pragma unroll
        for (int rr = 0; rr < 4; ++rr)
          #pragma unroll
          for (int cc = 0; cc < 8; ++cc) feat[rr][cc] = acc[rr][cc];
      } else if (lay == 0) {
        // threads only touch their OWN output cells of xs -> no barrier needed
        #pragma unroll
        for (int rr = 0; rr < 4; ++rr) {
          float4 a = make_float4(silu_f(acc[rr][0]), silu_f(acc[rr][1]),
                                 silu_f(acc[rr][2]), silu_f(acc[rr][3]));
          float4 b = make_float4(silu_f(acc[rr][4]), silu_f(acc[rr][5]),
                                 silu_f(acc[rr][6]), silu_f(acc[rr][7]));
          *(float4*)&xs[(r0 + rr) * XSTR + c0]     = a;
          *(float4*)&xs[(r0 + rr) * XSTR + c0 + 4] = b;
        }
      } else {
        #pragma unroll
        for (int rr = 0; rr < 4; ++rr) {
          float4 o0 = *(const float4*)&xs[(r0 + rr) * XSTR + c0];
          float4 o1 = *(const float4*)&xs[(r0 + rr) * XSTR + c0 + 4];
          float4 a = make_float4(o0.x + silu_f(acc[rr][0]), o0.y + silu_f(acc[rr][1]),
                                 o0.z + silu_f(acc[rr][2]), o0.w + silu_f(acc[rr][3]));
          float4 b = make_float4(o1.x + silu_f(acc[rr][4]), o1.y + silu_f(acc[rr][5]),
                                 o1.z + silu_f(acc[rr][6]), o1.w + silu_f(acc[rr][7]));
          *(float4*)&xs[(r0 + rr) * XSTR + c0]     = a;
          *(float4*)&xs[(r0 + rr) * XSTR + c0 + 4] = b;
        }
      }
    }

    // ---- smeared gaussians: smb[64][52] (cols 50,51 zero-padded) ----
    #pragma unroll 1
    for (int f = t; f < TR * SSTR; f += 256) {   // 3328 = 13*256 exactly
      int r = f / SSTR, g = f - r * SSTR;
      float v = 0.0f;
      if (g < NG) { float dd = dist[r0g + r] - (float)g * step; v = __expf(coeff * dd * dd); }
      smb[f] = v;
    }

    // ---- rbf GEMM: acc2 = smb[64][52] @ rbf_w[52][128] ----
    float acc2[4][8];
    #pragma unroll
    for (int rr = 0; rr < 4; ++rr)
      #pragma unroll
      for (int cc = 0; cc < 8; ++cc) acc2[rr][cc] = 0.0f;

    stage_w32(wt, rbf, t);            // rows 0..31
    if (t < E) headb[t] = head[t];
    __syncthreads();
    gemm_acc<32>(smb, SSTR, wt, acc2, r0, c0);
    __syncthreads();
    {                                  // rows 32..51 (zeros for g>=50)
      const float4* g4 = (const float4*)(rbf + 32 * E);
      float4* s4 = (float4*)wt;
      #pragma unroll
      for (int i = 0; i < 3; ++i) {
        int f = t + 256 * i;
        if (f < 20 * 32) {
          int g = f >> 5;
          float4 v = (32 + g < NG) ? g4[f] : make_float4(0.f, 0.f, 0.f, 0.f);
          s4[f] = v;
        }
      }
    }
    __syncthreads();
    gemm_acc<20>(smb + 32, SSTR, wt, acc2, r0, c0);

    // ---- head dot + masked per-row scalar ----
    #pragma unroll
    for (int rr = 0; rr < 4; ++rr) {
      float p = 0.0f;
      #pragma unroll
      for (int cc = 0; cc < 8; ++cc)
        p += feat[rr][cc] * acc2[rr][cc] * headb[c0 + cc];
      #pragma unroll
      for (int m = 1; m < 16; m <<= 1) p += __shfl_xor(p, m);
      if (cg == 0) {
        long row = r0g + r0 + rr;
        outw[row] = p * mask[row];
      }
    }
  }
}

__global__ __launch_bounds__(256) void energy_kernel(const float* __restrict__ em,
                                                     float* __restrict__ out) {
  __shared__ float red[256];
  int b = blockIdx.x, t = threadIdx.x;
  float s = 0.0f;
  for (int p = t; p < A_DIM * A_DIM; p += 256) s += em[(long)p * B_DIM + b];
  red[t] = s; __syncthreads();
  for (int off = 128; off > 0; off >>= 1) {
    if (t < off) red[t] += red[t + off];
    __syncthreads();
  }
  if (t == 0) out[b] = red[0] * (1.0f / 3600.0f);
}

__global__ __launch_bounds__(256) void forces_kernel(const float* __restrict__ fm,
                                                     const float* __restrict__ vh,
                                                     float* __restrict__ out) {
  int o = blockIdx.x * 256 + threadIdx.x;   // 24576 outputs = [j][b][c]
  if (o >= A_DIM * B_DIM * 3) return;
  int c = o % 3;
  int b = (o / 3) % B_DIM;
  int j = o / (B_DIM * 3);
  float s = 0.0f;
  #pragma unroll 4
  for (int i = 0; i < A_DIM; ++i) {
    long row = ((long)(i * A_DIM + j)) * B_DIM + b;
    s += fm[row] * vh[row * 3 + c];
  }
  out[B_DIM + o] = s * (1.0f / 60.0f);
}

extern "C" void kernel_launch(void* const* d_in, const int* in_sizes, int n_in,
                              void* d_out, int out_size, void* d_ws, size_t ws_size,
                              hipStream_t stream) {
  const float* T    = (const float*)d_in[0];
  const float* mask = (const float*)d_in[1];
  const float* dist = (const float*)d_in[2];
  const float* vh   = (const float*)d_in[3];
  const float* eWin = (const float*)d_in[4];
  const float* ebin = (const float*)d_in[5];
  const float* eWh  = (const float*)d_in[6];
  const float* ebh  = (const float*)d_in[7];
  const float* eWout= (const float*)d_in[8];
  const float* ebout= (const float*)d_in[9];
  const float* erbf = (const float*)d_in[10];
  const float* ehead= (const float*)d_in[11];
  const float* fWin = (const float*)d_in[12];
  const float* fbin = (const float*)d_in[13];
  const float* fWh  = (const float*)d_in[14];
  const float* fbh  = (const float*)d_in[15];
  const float* fWout= (const float*)d_in[16];
  const float* fbout= (const float*)d_in[17];
  const float* frbf = (const float*)d_in[18];
  const float* fhead= (const float*)d_in[19];

  float* em = (float*)d_ws;
  float* fm = em + NROW;
  float* out = (float*)d_out;

  fused_main<<<NROW / TR, 256, 0, stream>>>(
      T, mask, dist,
      eWin, ebin, eWh, ebh, eWout, ebout, erbf, ehead,
      fWin, fbin, fWh, fbh, fWout, fbout, frbf, fhead,
      em, fm);
  energy_kernel<<<B_DIM, 256, 0, stream>>>(em, out);
  forces_kernel<<<(A_DIM * B_DIM * 3) / 256, 256, 0, stream>>>(fm, vh, out);
}

// Round 2
// 2208.316 us; speedup vs baseline: 3.1179x; 3.1179x over previous
//
#include <hip/hip_runtime.h>

#define A_DIM 64
#define B_DIM 128
#define E 128
#define NG 50
#define NROW (A_DIM*A_DIM*B_DIM)   // 524288
#define TR 64                      // rows per block
#define XSTR 132                   // padded x-tile row stride
#define SSTR 52                    // smeared-gaussian tile row stride

__device__ __forceinline__ float silu_f(float x) {
  return x * __builtin_amdgcn_rcpf(1.0f + __expf(-x));
}

// async stage n4 float4s (16B/lane) from g into LDS buf via global_load_lds
__device__ __forceinline__ void stage_async(const float* g, float* buf, int n4, int t) {
  int wave = t >> 6, lane = t & 63;
  #pragma unroll
  for (int i = 0; i < 2; ++i) {
    int f4u = wave * 64 + i * 256;        // wave-uniform float4 index
    if (f4u < n4) {
      const float* gp = g + 4 * (f4u + lane);
      float* lp = buf + 4 * f4u;          // HW adds lane*16B
      __builtin_amdgcn_global_load_lds(
          (const __attribute__((address_space(1))) void*)gp,
          (__attribute__((address_space(3))) void*)lp, 16, 0, 0);
    }
  }
}

// acc[4][8] += x[r0..r0+3][0..KC) @ w[0..KC)[cols {c0a..c0a+3, c0b..c0b+3}]
template<int KC>
__device__ __forceinline__ void gemm_acc(const float* xbase, int xstr,
                                         const float* wt, float acc[4][8],
                                         int r0, int c0a, int c0b) {
  #pragma unroll
  for (int k4 = 0; k4 < KC; k4 += 4) {
    float4 xv[4];
    #pragma unroll
    for (int rr = 0; rr < 4; ++rr)
      xv[rr] = *(const float4*)(xbase + (r0 + rr) * xstr + k4);
    #pragma unroll
    for (int kk = 0; kk < 4; ++kk) {
      float4 wa = *(const float4*)(wt + (k4 + kk) * E + c0a);
      float4 wb = *(const float4*)(wt + (k4 + kk) * E + c0b);
      #pragma unroll
      for (int rr = 0; rr < 4; ++rr) {
        float xk = (kk == 0) ? xv[rr].x : (kk == 1) ? xv[rr].y
                 : (kk == 2) ? xv[rr].z : xv[rr].w;
        acc[rr][0] += xk * wa.x;
        acc[rr][1] += xk * wa.y;
        acc[rr][2] += xk * wa.z;
        acc[rr][3] += xk * wa.w;
        acc[rr][4] += xk * wb.x;
        acc[rr][5] += xk * wb.y;
        acc[rr][6] += xk * wb.z;
        acc[rr][7] += xk * wb.w;
      }
    }
  }
}

__global__ __launch_bounds__(256, 2) void fused_main(
    const float* __restrict__ T, const float* __restrict__ mask,
    const float* __restrict__ dist,
    const float* __restrict__ eWin, const float* __restrict__ ebin,
    const float* __restrict__ eWh,  const float* __restrict__ ebh,
    const float* __restrict__ eWout,const float* __restrict__ ebout,
    const float* __restrict__ erbf, const float* __restrict__ ehead,
    const float* __restrict__ fWin, const float* __restrict__ fbin,
    const float* __restrict__ fWh,  const float* __restrict__ fbh,
    const float* __restrict__ fWout,const float* __restrict__ fbout,
    const float* __restrict__ frbf, const float* __restrict__ fhead,
    float* __restrict__ em, float* __restrict__ fm)
{
  __shared__ __align__(16) float xs[TR * XSTR];     // 33792 B
  __shared__ __align__(16) float wbuf[2][16 * E];   // 16384 B
  __shared__ __align__(16) float smb[TR * SSTR];    // 13312 B
  __shared__ float headb[E];                        // 512 B -> 64000 B total

  const int t = threadIdx.x;
  const int rg = t >> 4, cg = t & 15;
  const int r0 = rg * 4;
  const int c0a = 4 * cg, c0b = 64 + 4 * cg;
  const long r0g = (long)blockIdx.x * TR;

  const float step = 12.0f / 49.0f;
  const float coeff = -0.5f / (step * step);

  for (int br = 0; br < 2; ++br) {
    const float* Win  = br ? fWin  : eWin;
    const float* bin  = br ? fbin  : ebin;
    const float* Wh   = br ? fWh   : eWh;
    const float* bh   = br ? fbh   : ebh;
    const float* Wout = br ? fWout : eWout;
    const float* bout = br ? fbout : ebout;
    const float* rbf  = br ? frbf  : erbf;
    const float* head = br ? fhead : ehead;
    float* outw = br ? fm : em;

    __syncthreads();                 // xs/smb/wbuf free for reuse

    stage_async(Win, wbuf[0], 512, t);   // chunk 0 DMA in flight

    // ---- load T tile (64 rows x 128) into xs ----
    {
      const float4* T4 = (const float4*)(T + r0g * E);
      #pragma unroll
      for (int i = 0; i < 8; ++i) {
        int f = t + 256 * i;         // 0..2047 float4s
        int r = f >> 5, c4 = f & 31;
        *(float4*)&xs[r * XSTR + c4 * 4] = T4[f];
      }
    }

    float feat[4][8];

    // ---- 4 dense layers, fused 32-chunk pipeline (16 k-rows per chunk) ----
    #pragma unroll 1
    for (int lay = 0; lay < 4; ++lay) {
      const float* bg = (lay == 0) ? bin : (lay == 1) ? bh
                       : (lay == 2) ? (bh + E) : bout;
      float4 ba = *(const float4*)(bg + c0a);
      float4 bb = *(const float4*)(bg + c0b);
      float acc[4][8];
      #pragma unroll
      for (int rr = 0; rr < 4; ++rr) {
        acc[rr][0] = ba.x; acc[rr][1] = ba.y; acc[rr][2] = ba.z; acc[rr][3] = ba.w;
        acc[rr][4] = bb.x; acc[rr][5] = bb.y; acc[rr][6] = bb.z; acc[rr][7] = bb.w;
      }

      #pragma unroll 1
      for (int ch = 0; ch < 8; ++ch) {
        __syncthreads();             // drains prev DMA + orders xs writes/reads
        int g = lay * 8 + ch;
        if (g + 1 < 32) {
          int gn = g + 1, ln = gn >> 3;
          const float* Wn = (ln == 0) ? Win : (ln == 1) ? Wh
                           : (ln == 2) ? (Wh + E * E) : Wout;
          stage_async(Wn + (gn & 7) * 16 * E, wbuf[gn & 1], 512, t);
        } else {
          stage_async(rbf, wbuf[0], 512, t);   // rbf rows 0..15
        }
        gemm_acc<16>(xs + ch * 16, XSTR, wbuf[g & 1], acc, r0, c0a, c0b);
      }
      __syncthreads();               // all xs reads of this layer done

      if (lay == 3) {
        #pragma unroll
        for (int rr = 0; rr < 4; ++rr)
          #pragma unroll
          for (int cc = 0; cc < 8; ++cc) feat[rr][cc] = acc[rr][cc];
      } else if (lay == 0) {
        #pragma unroll
        for (int rr = 0; rr < 4; ++rr) {
          float4 a = make_float4(silu_f(acc[rr][0]), silu_f(acc[rr][1]),
                                 silu_f(acc[rr][2]), silu_f(acc[rr][3]));
          float4 b = make_float4(silu_f(acc[rr][4]), silu_f(acc[rr][5]),
                                 silu_f(acc[rr][6]), silu_f(acc[rr][7]));
          *(float4*)&xs[(r0 + rr) * XSTR + c0a] = a;
          *(float4*)&xs[(r0 + rr) * XSTR + c0b] = b;
        }
      } else {
        #pragma unroll
        for (int rr = 0; rr < 4; ++rr) {
          float4 o0 = *(const float4*)&xs[(r0 + rr) * XSTR + c0a];
          float4 o1 = *(const float4*)&xs[(r0 + rr) * XSTR + c0b];
          float4 a = make_float4(o0.x + silu_f(acc[rr][0]), o0.y + silu_f(acc[rr][1]),
                                 o0.z + silu_f(acc[rr][2]), o0.w + silu_f(acc[rr][3]));
          float4 b = make_float4(o1.x + silu_f(acc[rr][4]), o1.y + silu_f(acc[rr][5]),
                                 o1.z + silu_f(acc[rr][6]), o1.w + silu_f(acc[rr][7]));
          *(float4*)&xs[(r0 + rr) * XSTR + c0a] = a;
          *(float4*)&xs[(r0 + rr) * XSTR + c0b] = b;
        }
      }
    }

    // ---- smeared gaussians: smb[64][52] (cols 50,51 zero) ----
    #pragma unroll 1
    for (int f = t; f < TR * SSTR; f += 256) {   // 3328 = 13*256
      int r = f / SSTR, gg = f - r * SSTR;
      float v = 0.0f;
      if (gg < NG) { float dd = dist[r0g + r] - (float)gg * step; v = __expf(coeff * dd * dd); }
      smb[f] = v;
    }
    if (t < E) headb[t] = head[t];

    // ---- rbf GEMM: acc2 = smb[64][50] @ rbf_w[50][128], 4 pipelined chunks ----
    float acc2[4][8];
    #pragma unroll
    for (int rr = 0; rr < 4; ++rr)
      #pragma unroll
      for (int cc = 0; cc < 8; ++cc) acc2[rr][cc] = 0.0f;

    #pragma unroll 1
    for (int rc = 0; rc < 4; ++rc) {
      __syncthreads();               // drains smb writes + rbf chunk DMA
      if (rc < 3) {
        // chunk rc+1: rows (rc+1)*16..; last chunk only 4 rows (48..51);
        // rows 50,51 read OOB-but-same-page, killed by smb zero cols.
        stage_async(rbf + (rc + 1) * 16 * E, wbuf[(rc + 1) & 1],
                    (rc + 1 == 3) ? 128 : 512, t);
      }
      if (rc < 3)
        gemm_acc<16>(smb + rc * 16, SSTR, wbuf[rc & 1], acc2, r0, c0a, c0b);
      else
        gemm_acc<4>(smb + 48, SSTR, wbuf[rc & 1], acc2, r0, c0a, c0b);
    }

    // ---- head dot + masked per-row scalar ----
    #pragma unroll
    for (int rr = 0; rr < 4; ++rr) {
      float p = 0.0f;
      #pragma unroll
      for (int cc = 0; cc < 8; ++cc) {
        int col = (cc < 4) ? (c0a + cc) : (c0b + cc - 4);
        p += feat[rr][cc] * acc2[rr][cc] * headb[col];
      }
      #pragma unroll
      for (int m = 1; m < 16; m <<= 1) p += __shfl_xor(p, m);
      if (cg == 0) {
        long row = r0g + r0 + rr;
        outw[row] = p * mask[row];
      }
    }
  }
}

__global__ __launch_bounds__(256) void energy_kernel(const float* __restrict__ em,
                                                     float* __restrict__ out) {
  __shared__ float red[256];
  int b = blockIdx.x, t = threadIdx.x;
  float s = 0.0f;
  for (int p = t; p < A_DIM * A_DIM; p += 256) s += em[(long)p * B_DIM + b];
  red[t] = s; __syncthreads();
  for (int off = 128; off > 0; off >>= 1) {
    if (t < off) red[t] += red[t + off];
    __syncthreads();
  }
  if (t == 0) out[b] = red[0] * (1.0f / 3600.0f);
}

__global__ __launch_bounds__(256) void forces_kernel(const float* __restrict__ fm,
                                                     const float* __restrict__ vh,
                                                     float* __restrict__ out) {
  int o = blockIdx.x * 256 + threadIdx.x;   // 24576 outputs = [j][b][c]
  if (o >= A_DIM * B_DIM * 3) return;
  int c = o % 3;
  int b = (o / 3) % B_DIM;
  int j = o / (B_DIM * 3);
  float s = 0.0f;
  #pragma unroll 4
  for (int i = 0; i < A_DIM; ++i) {
    long row = ((long)(i * A_DIM + j)) * B_DIM + b;
    s += fm[row] * vh[row * 3 + c];
  }
  out[B_DIM + o] = s * (1.0f / 60.0f);
}

extern "C" void kernel_launch(void* const* d_in, const int* in_sizes, int n_in,
                              void* d_out, int out_size, void* d_ws, size_t ws_size,
                              hipStream_t stream) {
  const float* T    = (const float*)d_in[0];
  const float* mask = (const float*)d_in[1];
  const float* dist = (const float*)d_in[2];
  const float* vh   = (const float*)d_in[3];
  const float* eWin = (const float*)d_in[4];
  const float* ebin = (const float*)d_in[5];
  const float* eWh  = (const float*)d_in[6];
  const float* ebh  = (const float*)d_in[7];
  const float* eWout= (const float*)d_in[8];
  const float* ebout= (const float*)d_in[9];
  const float* erbf = (const float*)d_in[10];
  const float* ehead= (const float*)d_in[11];
  const float* fWin = (const float*)d_in[12];
  const float* fbin = (const float*)d_in[13];
  const float* fWh  = (const float*)d_in[14];
  const float* fbh  = (const float*)d_in[15];
  const float* fWout= (const float*)d_in[16];
  const float* fbout= (const float*)d_in[17];
  const float* frbf = (const float*)d_in[18];
  const float* fhead= (const float*)d_in[19];

  float* em = (float*)d_ws;
  float* fm = em + NROW;
  float* out = (float*)d_out;

  fused_main<<<NROW / TR, 256, 0, stream>>>(
      T, mask, dist,
      eWin, ebin, eWh, ebh, eWout, ebout, erbf, ehead,
      fWin, fbin, fWh, fbh, fWout, fbout, frbf, fhead,
      em, fm);
  energy_kernel<<<B_DIM, 256, 0, stream>>>(em, out);
  forces_kernel<<<(A_DIM * B_DIM * 3) / 256, 256, 0, stream>>>(fm, vh, out);
}

// Round 4
// 1142.148 us; speedup vs baseline: 6.0284x; 1.9335x over previous
//
#include <hip/hip_runtime.h>

#define A_DIM 64
#define B_DIM 128
#define E 128
#define NG 50
#define NROW (A_DIM*A_DIM*B_DIM)   // 524288
#define TR 64                      // rows per block
#define KS 136                     // xa row stride (shorts) — 16B-aligned rows, uniform banks
#define WS 40                      // wc row stride (shorts) — 32 data + 8 pad (DMA 5-slot trick)
#define SMS 72                     // smb row stride (shorts)
#define BR_STRIDE 147456           // shorts per branch in prepped-weight region
#define RBF_OFF 131072             // short offset of rbf planes within a branch

using bf16x8  = __bf16 __attribute__((ext_vector_type(8)));
using short8v = short __attribute__((ext_vector_type(8)));
using f32x4   = float __attribute__((ext_vector_type(4)));

__device__ __forceinline__ float silu_f(float x) {
  return x * __builtin_amdgcn_rcpf(1.0f + __expf(-x));
}

__device__ __forceinline__ unsigned short bf16_rne(float v) {
  unsigned u = __float_as_uint(v);
  return (unsigned short)((u + 0x7FFFu + ((u >> 16) & 1u)) >> 16);
}
__device__ __forceinline__ void split2(float v, unsigned short& h, unsigned short& l) {
  h = bf16_rne(v);
  float fh = __uint_as_float(((unsigned)h) << 16);
  l = bf16_rne(v - fh);
}

// Stage one W k-chunk (2 planes x 128 rows x 32 k, rows padded to WS=40 shorts)
// via global_load_lds. 640 slots/plane, 5 slots per row (slot 4 = pad).
__device__ __forceinline__ void stage_chunk(const short* gbase, int plane_stride,
                                            int Kfull, int k0, short* lds,
                                            int wave, int lane) {
  #pragma unroll
  for (int i = 0; i < 5; ++i) {
    int g = wave + 4 * i;                 // 0..19, wave-uniform
    int p = (g >= 10) ? 1 : 0;            // plane: hi=0, lo=1
    int gg = g - p * 10;
    int slin = gg * 64 + lane;
    int n = (int)((unsigned)slin / 5u);   // row 0..127
    int s = slin - n * 5; s = (s > 3) ? 3 : s;
    const short* gp = gbase + p * plane_stride + n * Kfull + k0 + s * 8;
    short* lp = lds + p * (128 * WS) + gg * 512;    // HW adds lane*16B
    __builtin_amdgcn_global_load_lds(
        (const __attribute__((address_space(1))) void*)gp,
        (__attribute__((address_space(3))) void*)lp, 16, 0, 0);
  }
}

// One K=32 step: acc[rt][c] += split-fp32( x[64 x 32] @ W[32 x (wave's 32 cols)] )
__device__ __forceinline__ void gemm_step(const short* xhi, const short* xlo, int xstr,
                                          const short* wcb, int kcol,
                                          f32x4 acc[4][2], int wave, int lane) {
  const int m = lane & 15, o = lane >> 4;
  bf16x8 bh[2], bl[2];
  #pragma unroll
  for (int c = 0; c < 2; ++c) {
    int ng = (wave * 2 + c) * 16 + m;
    bh[c] = __builtin_bit_cast(bf16x8, *(const short8v*)(wcb + ng * WS + o * 8));
    bl[c] = __builtin_bit_cast(bf16x8, *(const short8v*)(wcb + 128 * WS + ng * WS + o * 8));
  }
  #pragma unroll
  for (int rt = 0; rt < 4; ++rt) {
    const short* ap = xhi + (rt * 16 + m) * xstr + kcol + o * 8;
    const short* lp = xlo + (rt * 16 + m) * xstr + kcol + o * 8;
    bf16x8 ah = __builtin_bit_cast(bf16x8, *(const short8v*)ap);
    bf16x8 al = __builtin_bit_cast(bf16x8, *(const short8v*)lp);
    #pragma unroll
    for (int c = 0; c < 2; ++c) {
      acc[rt][c] = __builtin_amdgcn_mfma_f32_16x16x32_bf16(al, bh[c], acc[rt][c], 0, 0, 0);
      acc[rt][c] = __builtin_amdgcn_mfma_f32_16x16x32_bf16(ah, bl[c], acc[rt][c], 0, 0, 0);
      acc[rt][c] = __builtin_amdgcn_mfma_f32_16x16x32_bf16(ah, bh[c], acc[rt][c], 0, 0, 0);
    }
  }
}

// Transpose + bf16 hi/lo split of all weight matrices into workspace.
// Dense: Wt[n][k] 128x128 per layer (hi plane, then lo). rbf: [n][64] zero-padded.
// 73728 threads per branch: 65536 dense + 8192 rbf (each thread writes hi AND lo).
__global__ __launch_bounds__(256) void prep_weights(
    const float* __restrict__ eWin, const float* __restrict__ eWh,
    const float* __restrict__ eWout, const float* __restrict__ erbf,
    const float* __restrict__ fWin, const float* __restrict__ fWh,
    const float* __restrict__ fWout, const float* __restrict__ frbf,
    short* __restrict__ S)
{
  int o = blockIdx.x * 256 + threadIdx.x;
  if (o >= 2 * 73728) return;
  int br = (o >= 73728) ? 1 : 0;
  int r = o - br * 73728;
  short* base = S + br * BR_STRIDE;
  float v; int dh;
  int lo_off;
  if (r < 65536) {
    int lay = r >> 14, idx = r & 16383, n = idx >> 7, k = idx & 127;
    const float* W = (lay == 0) ? (br ? fWin : eWin)
                   : (lay == 3) ? (br ? fWout : eWout)
                   : ((br ? fWh : eWh) + (lay - 1) * 16384);
    v = W[k * 128 + n];
    dh = lay * 32768 + n * 128 + k; lo_off = 16384;
  } else {
    int rr = r - 65536;                 // 0..8191
    int n = rr >> 6, k = rr & 63;       // n 0..127, k 0..63
    v = (k < NG) ? (br ? frbf : erbf)[k * 128 + n] : 0.0f;
    dh = RBF_OFF + n * 64 + k; lo_off = 8192;
  }
  unsigned short h, l; split2(v, h, l);
  base[dh] = (short)h;
  base[dh + lo_off] = (short)l;
}

__global__ __launch_bounds__(256, 2) void fused_main(
    const float* __restrict__ T, const float* __restrict__ mask,
    const float* __restrict__ dist,
    const float* __restrict__ ebin, const float* __restrict__ ebh,
    const float* __restrict__ ebout, const float* __restrict__ ehead,
    const float* __restrict__ fbin, const float* __restrict__ fbh,
    const float* __restrict__ fbout, const float* __restrict__ fhead,
    const short* __restrict__ S,
    float* __restrict__ em, float* __restrict__ fm)
{
  __shared__ short xa[2 * TR * KS];        // hi plane, lo plane: 34816 B
  __shared__ short wc[2][2 * 128 * WS];    // [buf][plane-major]: 40960 B
  __shared__ float part[4][TR];            // 1024 B  -> 76800 B total (2 blocks/CU)

  const int t = threadIdx.x;
  const int wave = t >> 6, lane = t & 63;
  const int q = lane >> 4, n16 = lane & 15;
  const int br = blockIdx.x & 1;
  const long tile = blockIdx.x >> 1;
  const long r0g = tile * TR;

  const short* Wp = S + br * BR_STRIDE;
  const float* bin  = br ? fbin : ebin;
  const float* bh_  = br ? fbh : ebh;
  const float* bout = br ? fbout : ebout;
  const float* head = br ? fhead : ehead;
  float* outw = br ? fm : em;

  short* xahi = xa;
  short* xalo = xa + TR * KS;

  const float stepv = 12.0f / 49.0f;
  const float coeff = -0.5f / (stepv * stepv);

  // chunk 0 (lay0, k 0..31) DMA in flight during T staging
  stage_chunk(Wp, 16384, 128, 0, wc[0], wave, lane);

  // ---- T tile -> xa hi/lo planes ----
  {
    int row = t >> 2, seg = t & 3;
    const float* Tp = T + (r0g + row) * E + seg * 32;
    short* ph = xahi + row * KS + seg * 32;
    short* pl = xalo + row * KS + seg * 32;
    #pragma unroll
    for (int j = 0; j < 8; ++j) {
      float4 v = *(const float4*)(Tp + j * 4);
      unsigned short h0,h1,h2,h3,l0,l1,l2,l3;
      split2(v.x,h0,l0); split2(v.y,h1,l1); split2(v.z,h2,l2); split2(v.w,h3,l3);
      *(short4*)(ph + j * 4) = make_short4((short)h0,(short)h1,(short)h2,(short)h3);
      *(short4*)(pl + j * 4) = make_short4((short)l0,(short)l1,(short)l2,(short)l3);
    }
  }

  float xres[4][2][4];
  f32x4 acc[4][2];

  // ---- 4 dense layers x 4 K-chunks, DMA double-buffered ----
  #pragma unroll 1
  for (int lay = 0; lay < 4; ++lay) {
    const float* bg = (lay == 0) ? bin : (lay == 3) ? bout : (bh_ + (lay - 1) * E);
    float b0 = bg[(wave * 2) * 16 + n16];
    float b1 = bg[(wave * 2 + 1) * 16 + n16];
    #pragma unroll
    for (int rt = 0; rt < 4; ++rt) {
      acc[rt][0] = (f32x4){b0, b0, b0, b0};
      acc[rt][1] = (f32x4){b1, b1, b1, b1};
    }
    #pragma unroll 1
    for (int ch = 0; ch < 4; ++ch) {
      __syncthreads();               // drains this chunk's DMA + orders xa writes
      int ci = lay * 4 + ch;
      if (ci < 15) {
        int cn = ci + 1;
        stage_chunk(Wp + (cn >> 2) * 32768, 16384, 128, (cn & 3) * 32,
                    wc[cn & 1], wave, lane);
      } else if (ci == 15) {
        stage_chunk(Wp + RBF_OFF, 8192, 64, 0, wc[0], wave, lane);  // rbf chunk0
      }
      gemm_step(xahi, xalo, KS, wc[ci & 1], ch * 32, acc, wave, lane);
    }
    if (lay < 3) {
      __syncthreads();               // all xa reads done before overwrite
      #pragma unroll
      for (int rt = 0; rt < 4; ++rt)
        #pragma unroll
        for (int c = 0; c < 2; ++c) {
          int col = (wave * 2 + c) * 16 + n16;
          #pragma unroll
          for (int i = 0; i < 4; ++i) {
            float v = silu_f(acc[rt][c][i]);
            if (lay > 0) v += xres[rt][c][i];
            xres[rt][c][i] = v;
            unsigned short h, l; split2(v, h, l);
            int row = rt * 16 + q * 4 + i;
            xahi[row * KS + col] = (short)h;
            xalo[row * KS + col] = (short)l;
          }
        }
    }
  }
  // acc now holds feat (Wout layer, bias included, no activation)

  __syncthreads();                   // drains rbf chunk0 DMA; xa reads (lay3) done
  stage_chunk(Wp + RBF_OFF, 8192, 64, 32, wc[1], wave, lane);  // rbf chunk1

  // ---- smeared gaussians -> smb hi/lo planes (overlay xa region) ----
  short* smhi = xa;
  short* smlo = xa + TR * SMS;
  {
    int r = t & 63, kg = t >> 6;
    float d = dist[r0g + r];
    #pragma unroll
    for (int j4 = 0; j4 < 4; ++j4) {
      unsigned short hs[4], ls[4];
      #pragma unroll
      for (int jj = 0; jj < 4; ++jj) {
        int k = kg * 16 + j4 * 4 + jj;
        float dd = d - (float)k * stepv;
        float v = (k < NG) ? __expf(coeff * dd * dd) : 0.0f;
        split2(v, hs[jj], ls[jj]);
      }
      *(short4*)(smhi + r * SMS + kg * 16 + j4 * 4) =
          make_short4((short)hs[0],(short)hs[1],(short)hs[2],(short)hs[3]);
      *(short4*)(smlo + r * SMS + kg * 16 + j4 * 4) =
          make_short4((short)ls[0],(short)ls[1],(short)ls[2],(short)ls[3]);
    }
  }
  float h0 = head[(wave * 2) * 16 + n16];
  float h1 = head[(wave * 2 + 1) * 16 + n16];

  f32x4 acc2[4][2];
  #pragma unroll
  for (int rt = 0; rt < 4; ++rt) {
    acc2[rt][0] = (f32x4){0.f, 0.f, 0.f, 0.f};
    acc2[rt][1] = (f32x4){0.f, 0.f, 0.f, 0.f};
  }
  __syncthreads();                   // smb visible + rbf chunk1 drained
  gemm_step(smhi, smlo, SMS, wc[0], 0,  acc2, wave, lane);
  gemm_step(smhi, smlo, SMS, wc[1], 32, acc2, wave, lane);

  // ---- head dot: per-row partials, cross-wave reduce via LDS ----
  #pragma unroll
  for (int rt = 0; rt < 4; ++rt)
    #pragma unroll
    for (int i = 0; i < 4; ++i) {
      float p = acc[rt][0][i] * acc2[rt][0][i] * h0
              + acc[rt][1][i] * acc2[rt][1][i] * h1;
      p += __shfl_xor(p, 1); p += __shfl_xor(p, 2);
      p += __shfl_xor(p, 4); p += __shfl_xor(p, 8);
      if (n16 == 0) part[wave][rt * 16 + q * 4 + i] = p;
    }
  __syncthreads();
  if (t < TR) {
    float pr = part[0][t] + part[1][t] + part[2][t] + part[3][t];
    outw[r0g + t] = pr * mask[r0g + t];
  }
}

__global__ __launch_bounds__(256) void energy_kernel(const float* __restrict__ em,
                                                     float* __restrict__ out) {
  __shared__ float red[256];
  int b = blockIdx.x, t = threadIdx.x;
  float s = 0.0f;
  for (int p = t; p < A_DIM * A_DIM; p += 256) s += em[(long)p * B_DIM + b];
  red[t] = s; __syncthreads();
  for (int off = 128; off > 0; off >>= 1) {
    if (t < off) red[t] += red[t + off];
    __syncthreads();
  }
  if (t == 0) out[b] = red[0] * (1.0f / 3600.0f);
}

__global__ __launch_bounds__(256) void forces_kernel(const float* __restrict__ fm,
                                                     const float* __restrict__ vh,
                                                     float* __restrict__ out) {
  int o = blockIdx.x * 256 + threadIdx.x;   // 24576 outputs = [j][b][c]
  if (o >= A_DIM * B_DIM * 3) return;
  int c = o % 3;
  int b = (o / 3) % B_DIM;
  int j = o / (B_DIM * 3);
  float s = 0.0f;
  #pragma unroll 4
  for (int i = 0; i < A_DIM; ++i) {
    long row = ((long)(i * A_DIM + j)) * B_DIM + b;
    s += fm[row] * vh[row * 3 + c];
  }
  out[B_DIM + o] = s * (1.0f / 60.0f);
}

extern "C" void kernel_launch(void* const* d_in, const int* in_sizes, int n_in,
                              void* d_out, int out_size, void* d_ws, size_t ws_size,
                              hipStream_t stream) {
  const float* T    = (const float*)d_in[0];
  const float* mask = (const float*)d_in[1];
  const float* dist = (const float*)d_in[2];
  const float* vh   = (const float*)d_in[3];
  const float* eWin = (const float*)d_in[4];
  const float* ebin = (const float*)d_in[5];
  const float* eWh  = (const float*)d_in[6];
  const float* ebh  = (const float*)d_in[7];
  const float* eWout= (const float*)d_in[8];
  const float* ebout= (const float*)d_in[9];
  const float* erbf = (const float*)d_in[10];
  const float* ehead= (const float*)d_in[11];
  const float* fWin = (const float*)d_in[12];
  const float* fbin = (const float*)d_in[13];
  const float* fWh  = (const float*)d_in[14];
  const float* fbh  = (const float*)d_in[15];
  const float* fWout= (const float*)d_in[16];
  const float* fbout= (const float*)d_in[17];
  const float* frbf = (const float*)d_in[18];
  const float* fhead= (const float*)d_in[19];

  float* em = (float*)d_ws;
  float* fm = em + NROW;
  short* S  = (short*)(fm + NROW);          // 4 MB + 576 KB used of d_ws
  float* out = (float*)d_out;

  prep_weights<<<576, 256, 0, stream>>>(eWin, eWh, eWout, erbf,
                                        fWin, fWh, fWout, frbf, S);
  fused_main<<<2 * (NROW / TR), 256, 0, stream>>>(
      T, mask, dist,
      ebin, ebh, ebout, ehead,
      fbin, fbh, fbout, fhead,
      S, em, fm);
  energy_kernel<<<B_DIM, 256, 0, stream>>>(em, out);
  forces_kernel<<<(A_DIM * B_DIM * 3) / 256, 256, 0, stream>>>(fm, vh, out);
}